// Round 16
// baseline (114.589 us; speedup 1.0000x reference)
//
#include <hip/hip_runtime.h>

typedef __attribute__((ext_vector_type(8))) short bf16x8;
typedef __attribute__((ext_vector_type(4))) float f32x4;
typedef __attribute__((ext_vector_type(16))) float f32x16;
typedef __attribute__((ext_vector_type(4))) unsigned short u16x4;
typedef __attribute__((ext_vector_type(8))) unsigned short u16x8;

#define DIM 1024
#define SEQ 2048
#define NHEAD 16
#define HDIM 64
// 0.125 * log2(e): folds the 1/sqrt(64) scale into exp2 space
#define C2 0.18033688011112042f

#define WAIT_VM4() asm volatile("s_waitcnt vmcnt(4)" ::: "memory")
#define WAIT_VM0() asm volatile("s_waitcnt vmcnt(0)" ::: "memory")
#define BAR() __builtin_amdgcn_s_barrier()
#define SCHEDB() __builtin_amdgcn_sched_barrier(0)

__device__ __forceinline__ unsigned short f2bf(float f) {
  union { float f; unsigned u; } v; v.f = f;
  unsigned r = v.u + 0x7fffu + ((v.u >> 16) & 1u);
  return (unsigned short)(r >> 16);
}

__device__ __forceinline__ float bf2f(unsigned short s) {
  union { unsigned u; float f; } v; v.u = ((unsigned)s) << 16;
  return v.f;
}

__device__ __forceinline__ void gload_lds16(const void* g, void* l) {
  __builtin_amdgcn_global_load_lds(
      (const __attribute__((address_space(1))) void*)g,
      (__attribute__((address_space(3))) void*)l, 16, 0, 0);
}

__device__ __forceinline__ f32x16 mfma32(bf16x8 a, bf16x8 b, f32x16 c) {
  return __builtin_amdgcn_mfma_f32_32x32x16_bf16(a, b, c, 0, 0, 0);
}

__device__ __forceinline__ unsigned cvtpk(float lo, float hi) {
  unsigned r;
  asm("v_cvt_pk_bf16_f32 %0, %1, %2" : "=v"(r) : "v"(lo), "v"(hi));
  return r;
}

// ---------------- fused fp32 -> bf16 conversion (x + 4 weights) ----------------
__global__ void f2bf_all(const float* __restrict__ x, const float* __restrict__ wq,
                         const float* __restrict__ wk, const float* __restrict__ wv,
                         const float* __restrict__ wo, unsigned short* __restrict__ xb,
                         unsigned short* __restrict__ wb) {
  int blk = blockIdx.x;
  const float* src;
  unsigned short* dst;
  int rb;
  if (blk < 4096) { src = x; dst = xb; rb = blk; }
  else {
    int w = (blk - 4096) >> 10;
    src = w == 0 ? wq : w == 1 ? wk : w == 2 ? wv : wo;
    dst = wb + (size_t)w * 1048576;
    rb = (blk - 4096) & 1023;
  }
  int i = rb * 256 + threadIdx.x;  // float4 index
  float4 v = ((const float4*)src)[i];
  u16x4 o;
  o[0] = f2bf(v.x); o[1] = f2bf(v.y); o[2] = f2bf(v.z); o[3] = f2bf(v.w);
  ((u16x4*)dst)[i] = o;
}

// ---------------- fused Q/K/VT projection GEMM: BK=32 dbuf, counted vmcnt -----
// (unchanged from round 13)
__global__ __launch_bounds__(256) void gemm3(
    const unsigned short* __restrict__ xb,
    const unsigned short* __restrict__ wb,
    unsigned short* __restrict__ qkv) {
  __shared__ unsigned short As[2][4096];
  __shared__ unsigned short Bs[2][4096];
  const int bz = blockIdx.x;
  const unsigned short *A, *B;
  unsigned short* C;
  int m0, n0, ldc;
  float cscale = 1.0f;
  if (bz < 512) {
    int xcd = bz & 7, inner = bz >> 3;
    int mm = inner & 3, n = (inner >> 2) & 7, w = inner >> 5;
    m0 = (xcd * 4 + mm) * 128; n0 = n * 128;
    A = xb; B = wb + w * 1048576; C = qkv + w * 4194304; ldc = 1024;
    if (w == 0) cscale = C2;
  } else {
    int idx = bz - 512;
    int xcd = idx & 7, inner = idx >> 3;
    int tt = inner & 3, mv = inner >> 2;
    m0 = mv * 128; n0 = (xcd * 4 + tt) * 128;
    A = wb + 2 * 1048576; B = xb; C = qkv + 2 * 4194304; ldc = 4096;
  }
  const int tid = threadIdx.x;
  const int wv = tid >> 6, lane = tid & 63;
  const int g = lane >> 4, l16 = lane & 15;
  const int wm = (wv >> 1) * 64, wn = (wv & 1) * 64;
  const int sro = lane >> 2, sc4 = lane & 3;  // staging: row-in-16 / chunk
  f32x4 acc[4][4] = {};

#define GSTAGE(IT, BUF)                                                        \
  {                                                                            \
    const int kt = (IT) * 32;                                                  \
    _Pragma("unroll")                                                          \
    for (int s = 0; s < 2; ++s) {                                              \
      int r = wv * 32 + s * 16 + sro;                                          \
      int cd = sc4 ^ ((r >> 1) & 3);                                           \
      gload_lds16(A + (long long)(m0 + r) * 1024 + kt + cd * 8,                \
                  &As[BUF][wv * 1024 + s * 512]);                              \
      gload_lds16(B + (long long)(n0 + r) * 1024 + kt + cd * 8,                \
                  &Bs[BUF][wv * 1024 + s * 512]);                              \
    }                                                                          \
  }

  GSTAGE(0, 0);
  GSTAGE(1, 1);

  for (int it = 0; it < 32; ++it) {
    const int buf = it & 1;
    WAIT_VM4();          // tile-it loads landed (tile-(it+1)'s stay in flight)
    BAR();               // all waves' tile-it staging complete
    SCHEDB();
    bf16x8 af[4], bfr[4];
#pragma unroll
    for (int mf = 0; mf < 4; ++mf) {
      int row = wm + mf * 16 + l16;
      af[mf] = *(const bf16x8*)((const char*)&As[buf][0] + row * 64 +
                                ((g ^ ((row >> 1) & 3)) << 4));
    }
#pragma unroll
    for (int nf = 0; nf < 4; ++nf) {
      int row = wn + nf * 16 + l16;
      bfr[nf] = *(const bf16x8*)((const char*)&Bs[buf][0] + row * 64 +
                                 ((g ^ ((row >> 1) & 3)) << 4));
    }
#pragma unroll
    for (int mf = 0; mf < 4; ++mf)
#pragma unroll
      for (int nf = 0; nf < 4; ++nf)
        acc[mf][nf] = __builtin_amdgcn_mfma_f32_16x16x32_bf16(
            af[mf], bfr[nf], acc[mf][nf], 0, 0, 0);
    SCHEDB();
    BAR();               // all waves done reading buf -> safe to overwrite
    if (it + 1 < 32) {
      int nx = (it + 2 < 32) ? it + 2 : 31;  // dup-stage keeps vmcnt FIFO exact
      GSTAGE(nx, buf);
    }
  }

#pragma unroll
  for (int mf = 0; mf < 4; ++mf)
#pragma unroll
    for (int nf = 0; nf < 4; ++nf)
#pragma unroll
      for (int r = 0; r < 4; ++r) {
        long long m = m0 + wm + mf * 16 + g * 4 + r;
        long long n = n0 + wn + nf * 16 + l16;
        C[m * ldc + n] = f2bf(acc[mf][nf][r] * cscale);
      }
}

// ---------------- NT GEMM (f32 out), BK=32 dbuf, counted vmcnt ----------------
// (unchanged from round 13)
__global__ __launch_bounds__(256) void gemm_out(
    const unsigned short* __restrict__ A,
    const unsigned short* __restrict__ B,
    float* __restrict__ C) {
  __shared__ unsigned short As[2][4096];
  __shared__ unsigned short Bs[2][4096];
  const int tid = threadIdx.x;
  const int wv = tid >> 6, lane = tid & 63;
  const int g = lane >> 4, l16 = lane & 15;
  const int m0 = blockIdx.y * 128, n0 = blockIdx.x * 128;
  const int wm = (wv >> 1) * 64, wn = (wv & 1) * 64;
  const int sro = lane >> 2, sc4 = lane & 3;
  f32x4 acc[4][4] = {};

#define OSTAGE(IT, BUF)                                                        \
  {                                                                            \
    const int kt = (IT) * 32;                                                  \
    _Pragma("unroll")                                                          \
    for (int s = 0; s < 2; ++s) {                                              \
      int r = wv * 32 + s * 16 + sro;                                          \
      int cd = sc4 ^ ((r >> 1) & 3);                                           \
      gload_lds16(A + (long long)(m0 + r) * 1024 + kt + cd * 8,                \
                  &As[BUF][wv * 1024 + s * 512]);                              \
      gload_lds16(B + (long long)(n0 + r) * 1024 + kt + cd * 8,                \
                  &Bs[BUF][wv * 1024 + s * 512]);                              \
    }                                                                          \
  }

  OSTAGE(0, 0);
  OSTAGE(1, 1);

  for (int it = 0; it < 32; ++it) {
    const int buf = it & 1;
    WAIT_VM4();
    BAR();
    SCHEDB();
    bf16x8 af[4], bfr[4];
#pragma unroll
    for (int mf = 0; mf < 4; ++mf) {
      int row = wm + mf * 16 + l16;
      af[mf] = *(const bf16x8*)((const char*)&As[buf][0] + row * 64 +
                                ((g ^ ((row >> 1) & 3)) << 4));
    }
#pragma unroll
    for (int nf = 0; nf < 4; ++nf) {
      int row = wn + nf * 16 + l16;
      bfr[nf] = *(const bf16x8*)((const char*)&Bs[buf][0] + row * 64 +
                                 ((g ^ ((row >> 1) & 3)) << 4));
    }
#pragma unroll
    for (int mf = 0; mf < 4; ++mf)
#pragma unroll
      for (int nf = 0; nf < 4; ++nf)
        acc[mf][nf] = __builtin_amdgcn_mfma_f32_16x16x32_bf16(
            af[mf], bfr[nf], acc[mf][nf], 0, 0, 0);
    SCHEDB();
    BAR();
    if (it + 1 < 32) {
      int nx = (it + 2 < 32) ? it + 2 : 31;
      OSTAGE(nx, buf);
    }
  }

#pragma unroll
  for (int mf = 0; mf < 4; ++mf)
#pragma unroll
    for (int nf = 0; nf < 4; ++nf)
#pragma unroll
      for (int r = 0; r < 4; ++r) {
        long long m = m0 + wm + mf * 16 + g * 4 + r;
        long long n = n0 + wn + nf * 16 + l16;
        C[m * 1024 + n] = acc[mf][nf][r];
      }
}

// ---------------- flash attention, split-K, chunk=6, fixed-ref softmax --------
// Round 15 inner loop EXACTLY; chunking refined 8->6 k-tiles per block for finer
// LPT granules: cn(qt) = ceil((2qt+2)/6), 51 chunks/(b,h) -> grid (51,16,2) =
// 1632 blocks (~6.4/CU). qt<=2 single-chunk (direct O write); qt>=3 write
// unnormalized partials (48 slots/(b,h)); slots 0..511 reuse the dead xb buffer.
__global__ __launch_bounds__(256, 4) void attn_kernel(
    const unsigned short* __restrict__ Qg,
    const unsigned short* __restrict__ Kg,
    const unsigned short* __restrict__ VTg,
    unsigned short* __restrict__ Og,
    unsigned short* __restrict__ pacc1,
    unsigned short* __restrict__ pacc2,
    float* __restrict__ pml) {
  __shared__ unsigned short Kls[2][4096];  // [buf][key 64][d 64] (chunk-swizzled)
  __shared__ unsigned short Vls[2][4096];  // [buf][d 64][key 64] (chunk-swizzled)

  const int tid = threadIdx.x;
  const int wv = tid >> 6, lane = tid & 63;
  const int l32 = lane & 31, hi = lane >> 5;
  const int h = blockIdx.y, b = blockIdx.z;

  // chunk decode, longest-qt first (LPT): walk qt 15..0, cn(qt)=(2qt+7)/6
  int ii = blockIdx.x;  // [0,51)
  int qt = 15, c = 0;
  for (;; --qt) {
    int cnq = (2 * qt + 7) / 6;
    if (ii < cnq) { c = ii; break; }
    ii -= cnq;
  }
  const int cn = (2 * qt + 7) / 6;

  const int nt = 2 * qt + 2;
  const int t0 = c * 6;
  const int tb = min(t0 + 6, nt);   // block stage bound
  const int umax = 4 * qt + wv;     // last 32-key sub-tile this wave computes

  const int q = qt * 128 + wv * 32 + l32;
  const long long bh = (long long)b * SEQ * DIM + h * HDIM;
  const long long vbase = (long long)h * HDIM * 4096 + b * SEQ;

  // Q fragments (B-operand): B[col=q][k = hi*8+j], per 16-d slice
  const unsigned short* Qrow = Qg + (long long)(b * SEQ + q) * DIM + h * HDIM;
  bf16x8 qf[4];
#pragma unroll
  for (int ds = 0; ds < 4; ++ds)
    qf[ds] = *(const bf16x8*)(Qrow + ds * 16 + hi * 8);
  WAIT_VM0();  // drain Q loads so the staging vmcnt counts are exact

  // all-ones bf16 A-fragment for the l-accumulating MFMA
  bf16x8 ones;
#pragma unroll
  for (int j = 0; j < 8; ++j) ones[j] = (short)0x3F80;

  f32x16 acc0 = {}, acc1 = {}, lacc = {};

  // stage: wave wv loads K chunks {2wv,2wv+1} and V chunks {2wv,2wv+1}
  // (chunk j = 8 rows of 128 B; linear LDS dest, inverse-swizzled global source)
  const int sr = lane >> 3, sc = lane & 7;
#define STAGE(T, BUF)                                                          \
  {                                                                            \
    const int kv0s = (T) * 64;                                                 \
    _Pragma("unroll")                                                          \
    for (int s = 0; s < 2; ++s) {                                              \
      int jj = wv * 2 + s;                                                     \
      int r = jj * 8 + sr;                                                     \
      int cs = (sc ^ (r & 7)) * 8;                                             \
      gload_lds16(Kg + bh + (long long)(kv0s + r) * DIM + cs,                  \
                  &Kls[BUF][jj * 512]);                                        \
      gload_lds16(VTg + vbase + (long long)r * 4096 + kv0s + cs,               \
                  &Vls[BUF][jj * 512]);                                        \
    }                                                                          \
  }

  STAGE(t0, 0);
  { int nx = (t0 + 1 < tb) ? t0 + 1 : tb - 1; STAGE(nx, 1); }  // dup ok, unread

  for (int t = t0; t < tb; ++t) {
    const int buf = (t - t0) & 1;
    WAIT_VM4();          // tile-t loads landed (t+1's stay in flight)
    BAR();               // all waves' tile-t staging complete
    SCHEDB();

#pragma unroll
    for (int s = 0; s < 2; ++s) {
      const int u = 2 * t + s;
      if (u <= umax) {
        // --- QK^T for 32 keys (windowed K reads) ---
        f32x16 sv = {};
        __builtin_amdgcn_s_setprio(1);
#pragma unroll
        for (int ds = 0; ds < 4; ++ds) {
          const int cbk = (((ds << 1) | hi) ^ (l32 & 7)) * 16;
          bf16x8 kf = *(const bf16x8*)((const char*)&Kls[buf][0] +
                                       (s * 32 + l32) * 128 + cbk);
          sv = mfma32(kf, qf[ds], sv);
        }
        __builtin_amdgcn_s_setprio(0);

        // --- causal mask (only the diagonal sub-tile; key base == q base) ---
        if (u == umax) {
#pragma unroll
          for (int r = 0; r < 16; ++r) {
            int kw = (r & 3) + 8 * (r >> 2) + 4 * hi;  // key within 32-block
            if (kw > l32) sv[r] = -1e30f;
          }
        }

        // --- p = exp2(s): single v_exp_f32 (fixed ref; normalization cancels)
#pragma unroll
        for (int r = 0; r < 16; ++r) sv[r] = __builtin_amdgcn_exp2f(sv[r]);

        // --- P -> bf16 B-fragments (in-register) + PV + l via ones-MFMA ---
        __builtin_amdgcn_s_setprio(1);
#pragma unroll
        for (int kk = 0; kk < 2; ++kk) {
          const int base = kk * 8;
          unsigned a0 = cvtpk(sv[base + 0], sv[base + 1]);
          unsigned a1 = cvtpk(sv[base + 2], sv[base + 3]);
          unsigned a2 = cvtpk(sv[base + 4], sv[base + 5]);
          unsigned a3 = cvtpk(sv[base + 6], sv[base + 7]);
          asm("v_permlane32_swap_b32 %0, %1" : "+v"(a0), "+v"(a2));
          asm("v_permlane32_swap_b32 %0, %1" : "+v"(a1), "+v"(a3));
          union { unsigned u4[4]; bf16x8 v; } pf;
          pf.u4[0] = a0; pf.u4[1] = a1; pf.u4[2] = a2; pf.u4[3] = a3;
          const int slice = 2 * s + kk;  // 16-key slice within the 64-key tile
          const int cbv = (((slice << 1) | hi) ^ (l32 & 7)) * 16;
          bf16x8 v0 = *(const bf16x8*)((const char*)&Vls[buf][0] + l32 * 128 + cbv);
          bf16x8 v1 = *(const bf16x8*)((const char*)&Vls[buf][0] + (32 + l32) * 128 + cbv);
          acc0 = mfma32(v0, pf.v, acc0);
          acc1 = mfma32(v1, pf.v, acc1);
          lacc = mfma32(ones, pf.v, lacc);
        }
        __builtin_amdgcn_s_setprio(0);
      }
    }
    SCHEDB();
    BAR();               // all waves done reading buf -> safe to overwrite
    if (t + 1 < tb) {
      int nx = (t + 2 < tb) ? t + 2 : tb - 1;  // dup-stage keeps FIFO exact
      STAGE(nx, buf);
    }
  }

  const float l_run = lacc[0];  // every row of lacc holds the column sum l(q)

  if (cn == 1) {
    // --- direct epilogue: O[b, q, h*64 + d] = acc^T / l (cvt_pk packing) ---
    const float inv_l = 1.0f / l_run;
    unsigned short* Orow = Og + (long long)(b * SEQ + q) * DIM + h * HDIM;
#pragma unroll
    for (int dblk = 0; dblk < 2; ++dblk) {
#pragma unroll
      for (int g4 = 0; g4 < 4; ++g4) {
        float v0 = (dblk ? acc1[g4 * 4 + 0] : acc0[g4 * 4 + 0]) * inv_l;
        float v1 = (dblk ? acc1[g4 * 4 + 1] : acc0[g4 * 4 + 1]) * inv_l;
        float v2 = (dblk ? acc1[g4 * 4 + 2] : acc0[g4 * 4 + 2]) * inv_l;
        float v3 = (dblk ? acc1[g4 * 4 + 3] : acc0[g4 * 4 + 3]) * inv_l;
        union { unsigned u[2]; u16x4 v; } o;
        o.u[0] = cvtpk(v0, v1);
        o.u[1] = cvtpk(v2, v3);
        *(u16x4*)(Orow + dblk * 32 + 8 * g4 + 4 * hi) = o.v;
      }
    }
  } else {
    // --- partial epilogue: unnormalized acc (bf16, cvt_pk) + l (f32) ---
    int sbase = 0;
    for (int j = 3; j < qt; ++j) sbase += (2 * j + 7) / 6;
    const int slot = (b * NHEAD + h) * 48 + sbase + c;
    unsigned short* sp = (slot < 512) ? pacc1 + (size_t)slot * 8192
                                      : pacc2 + (size_t)(slot - 512) * 8192;
    unsigned short* pbase = sp + (wv * 32 + l32) * 64;
#pragma unroll
    for (int dblk = 0; dblk < 2; ++dblk) {
#pragma unroll
      for (int g4 = 0; g4 < 4; ++g4) {
        float v0 = dblk ? acc1[g4 * 4 + 0] : acc0[g4 * 4 + 0];
        float v1 = dblk ? acc1[g4 * 4 + 1] : acc0[g4 * 4 + 1];
        float v2 = dblk ? acc1[g4 * 4 + 2] : acc0[g4 * 4 + 2];
        float v3 = dblk ? acc1[g4 * 4 + 3] : acc0[g4 * 4 + 3];
        union { unsigned u[2]; u16x4 v; } o;
        o.u[0] = cvtpk(v0, v1);
        o.u[1] = cvtpk(v2, v3);
        *(u16x4*)(pbase + dblk * 32 + 8 * g4 + 4 * hi) = o.v;
      }
    }
    if (hi == 0) pml[slot * 128 + wv * 32 + l32] = l_run;
  }
}

// ---------------- split-K merge: plain sum of 2-6 partials per (b,h,qt>=3) ----
__global__ __launch_bounds__(256) void attn_merge(
    const unsigned short* __restrict__ pacc1,
    const unsigned short* __restrict__ pacc2,
    const float* __restrict__ pml,
    unsigned short* __restrict__ Og) {
  const int qt = 3 + blockIdx.x;  // 3..15
  const int h = blockIdx.y, b = blockIdx.z;
  const int cn = (2 * qt + 7) / 6;
  int sbase = 0;
  for (int j = 3; j < qt; ++j) sbase += (2 * j + 7) / 6;
  const int base_slot = (b * NHEAD + h) * 48 + sbase;
  const int t = threadIdx.x;
  const int ql = t >> 1, d0 = (t & 1) * 32;

  float L = 0.f;
#pragma unroll
  for (int cc = 0; cc < 6; ++cc)
    if (cc < cn) L += pml[(base_slot + cc) * 128 + ql];
  const float invL = 1.0f / L;

  float o[32] = {};
#pragma unroll
  for (int cc = 0; cc < 6; ++cc)
    if (cc < cn) {
      const int s = base_slot + cc;
      const unsigned short* p =
          ((s < 512) ? pacc1 + (size_t)s * 8192
                     : pacc2 + (size_t)(s - 512) * 8192) + (size_t)ql * 64 + d0;
#pragma unroll
      for (int k = 0; k < 32; k += 8) {
        u16x8 v = *(const u16x8*)(p + k);
#pragma unroll
        for (int jv = 0; jv < 8; ++jv) o[k + jv] += bf2f(v[jv]);
      }
    }

  const int q = qt * 128 + ql;
  unsigned short* orow = Og + (size_t)(b * SEQ + q) * DIM + h * HDIM + d0;
#pragma unroll
  for (int k = 0; k < 32; k += 8) {
    union { unsigned u[4]; u16x8 v; } ov;
#pragma unroll
    for (int jv = 0; jv < 4; ++jv)
      ov.u[jv] = cvtpk(o[k + 2 * jv] * invL, o[k + 2 * jv + 1] * invL);
    *(u16x8*)(orow + k) = ov.v;
  }
}

// ---------------- launcher ----------------
extern "C" void kernel_launch(void* const* d_in, const int* in_sizes, int n_in,
                              void* d_out, int out_size, void* d_ws, size_t ws_size,
                              hipStream_t stream) {
  const float* x   = (const float*)d_in[0];
  const float* wq  = (const float*)d_in[2];
  const float* wk  = (const float*)d_in[3];
  const float* wv_ = (const float*)d_in[4];
  const float* wo  = (const float*)d_in[5];

  unsigned short* xb  = (unsigned short*)d_ws;            // [4096][1024]; reused as pacc slots 0..511
  unsigned short* wb  = xb + (size_t)4096 * 1024;         // [4][1024][1024] q,k,v,o
  unsigned short* qkv = wb + (size_t)4 * 1024 * 1024;     // Q,K [4096][1024]; VT [1024][4096]
  unsigned short* ao  = qkv + (size_t)3 * 4096 * 1024;    // [4096][1024]
  unsigned short* pacc2 = ao + (size_t)4096 * 1024;       // slots 512..1535 (16 KB each)
  float* pml = (float*)(pacc2 + (size_t)1024 * 8192);     // [1536][128] f32 l

  f2bf_all<<<8192, 256, 0, stream>>>(x, wq, wk, wv_, wo, xb, wb);

  // Q, K, V^T projections in ONE launch (768 blocks); Q pre-scaled by C2
  gemm3<<<768, 256, 0, stream>>>(xb, wb, qkv);

  attn_kernel<<<dim3(51, 16, 2), 256, 0, stream>>>(
      qkv, qkv + 4194304, qkv + 2 * 4194304, ao, xb, pacc2, pml);

  attn_merge<<<dim3(13, 16, 2), 256, 0, stream>>>(xb, pacc2, pml, ao);

  // output projection -> fp32 d_out
  gemm_out<<<dim3(8, 32, 1), 256, 0, stream>>>(ao, wb + 3145728, (float*)d_out);
}

// Round 17
// 110.300 us; speedup vs baseline: 1.0389x; 1.0389x over previous
//
#include <hip/hip_runtime.h>

typedef __attribute__((ext_vector_type(8))) short bf16x8;
typedef __attribute__((ext_vector_type(4))) float f32x4;
typedef __attribute__((ext_vector_type(16))) float f32x16;
typedef __attribute__((ext_vector_type(4))) unsigned short u16x4;
typedef __attribute__((ext_vector_type(8))) unsigned short u16x8;

#define DIM 1024
#define SEQ 2048
#define NHEAD 16
#define HDIM 64
// 0.125 * log2(e): folds the 1/sqrt(64) scale into exp2 space
#define C2 0.18033688011112042f

#define WAIT_VM4() asm volatile("s_waitcnt vmcnt(4)" ::: "memory")
#define WAIT_VM3() asm volatile("s_waitcnt vmcnt(3)" ::: "memory")
#define WAIT_VM0() asm volatile("s_waitcnt vmcnt(0)" ::: "memory")
#define BAR() __builtin_amdgcn_s_barrier()
#define SCHEDB() __builtin_amdgcn_sched_barrier(0)

__device__ __forceinline__ unsigned short f2bf(float f) {
  union { float f; unsigned u; } v; v.f = f;
  unsigned r = v.u + 0x7fffu + ((v.u >> 16) & 1u);
  return (unsigned short)(r >> 16);
}

__device__ __forceinline__ float bf2f(unsigned short s) {
  union { unsigned u; float f; } v; v.u = ((unsigned)s) << 16;
  return v.f;
}

__device__ __forceinline__ void gload_lds16(const void* g, void* l) {
  __builtin_amdgcn_global_load_lds(
      (const __attribute__((address_space(1))) void*)g,
      (__attribute__((address_space(3))) void*)l, 16, 0, 0);
}

__device__ __forceinline__ f32x16 mfma32(bf16x8 a, bf16x8 b, f32x16 c) {
  return __builtin_amdgcn_mfma_f32_32x32x16_bf16(a, b, c, 0, 0, 0);
}

__device__ __forceinline__ unsigned cvtpk(float lo, float hi) {
  unsigned r;
  asm("v_cvt_pk_bf16_f32 %0, %1, %2" : "=v"(r) : "v"(lo), "v"(hi));
  return r;
}

// ---------------- fused fp32 -> bf16 conversion (x + 4 weights) ----------------
__global__ void f2bf_all(const float* __restrict__ x, const float* __restrict__ wq,
                         const float* __restrict__ wk, const float* __restrict__ wv,
                         const float* __restrict__ wo, unsigned short* __restrict__ xb,
                         unsigned short* __restrict__ wb) {
  int blk = blockIdx.x;
  const float* src;
  unsigned short* dst;
  int rb;
  if (blk < 4096) { src = x; dst = xb; rb = blk; }
  else {
    int w = (blk - 4096) >> 10;
    src = w == 0 ? wq : w == 1 ? wk : w == 2 ? wv : wo;
    dst = wb + (size_t)w * 1048576;
    rb = (blk - 4096) & 1023;
  }
  int i = rb * 256 + threadIdx.x;  // float4 index
  float4 v = ((const float4*)src)[i];
  u16x4 o;
  o[0] = f2bf(v.x); o[1] = f2bf(v.y); o[2] = f2bf(v.z); o[3] = f2bf(v.w);
  ((u16x4*)dst)[i] = o;
}

// ---------------- fused Q/K/VT projection GEMM: BK=32 dbuf, counted vmcnt -----
// Round 13 pipeline + pointer-increment staging (addresses advance by +32
// elements per K-step; no per-iter 64-bit muls).
__global__ __launch_bounds__(256) void gemm3(
    const unsigned short* __restrict__ xb,
    const unsigned short* __restrict__ wb,
    unsigned short* __restrict__ qkv) {
  __shared__ unsigned short As[2][4096];
  __shared__ unsigned short Bs[2][4096];
  const int bz = blockIdx.x;
  const unsigned short *A, *B;
  unsigned short* C;
  int m0, n0, ldc;
  float cscale = 1.0f;
  if (bz < 512) {
    int xcd = bz & 7, inner = bz >> 3;
    int mm = inner & 3, n = (inner >> 2) & 7, w = inner >> 5;
    m0 = (xcd * 4 + mm) * 128; n0 = n * 128;
    A = xb; B = wb + w * 1048576; C = qkv + w * 4194304; ldc = 1024;
    if (w == 0) cscale = C2;
  } else {
    int idx = bz - 512;
    int xcd = idx & 7, inner = idx >> 3;
    int tt = inner & 3, mv = inner >> 2;
    m0 = mv * 128; n0 = (xcd * 4 + tt) * 128;
    A = wb + 2 * 1048576; B = xb; C = qkv + 2 * 4194304; ldc = 4096;
  }
  const int tid = threadIdx.x;
  const int wv = tid >> 6, lane = tid & 63;
  const int g = lane >> 4, l16 = lane & 15;
  const int wm = (wv >> 1) * 64, wn = (wv & 1) * 64;
  const int sro = lane >> 2, sc4 = lane & 3;  // staging: row-in-16 / chunk
  f32x4 acc[4][4] = {};

  // staging pointers (advance +32 elements per stage)
  const int rA0 = wv * 32 + sro, rA1 = wv * 32 + 16 + sro;
  const int cd0 = (sc4 ^ ((rA0 >> 1) & 3)) * 8, cd1 = (sc4 ^ ((rA1 >> 1) & 3)) * 8;
  const unsigned short* Ap0 = A + (long long)(m0 + rA0) * 1024 + cd0;
  const unsigned short* Ap1 = A + (long long)(m0 + rA1) * 1024 + cd1;
  const unsigned short* Bp0 = B + (long long)(n0 + rA0) * 1024 + cd0;
  const unsigned short* Bp1 = B + (long long)(n0 + rA1) * 1024 + cd1;

#define GSTAGE(BUF)                                                            \
  {                                                                            \
    gload_lds16(Ap0, &As[BUF][wv * 1024]);                                     \
    gload_lds16(Ap1, &As[BUF][wv * 1024 + 512]);                               \
    gload_lds16(Bp0, &Bs[BUF][wv * 1024]);                                     \
    gload_lds16(Bp1, &Bs[BUF][wv * 1024 + 512]);                               \
    Ap0 += 32; Ap1 += 32; Bp0 += 32; Bp1 += 32;                                \
  }

  GSTAGE(0);
  GSTAGE(1);

  for (int it = 0; it < 32; ++it) {
    const int buf = it & 1;
    WAIT_VM4();          // tile-it loads landed (tile-(it+1)'s stay in flight)
    BAR();               // all waves' tile-it staging complete
    SCHEDB();
    bf16x8 af[4], bfr[4];
#pragma unroll
    for (int mf = 0; mf < 4; ++mf) {
      int row = wm + mf * 16 + l16;
      af[mf] = *(const bf16x8*)((const char*)&As[buf][0] + row * 64 +
                                ((g ^ ((row >> 1) & 3)) << 4));
    }
#pragma unroll
    for (int nf = 0; nf < 4; ++nf) {
      int row = wn + nf * 16 + l16;
      bfr[nf] = *(const bf16x8*)((const char*)&Bs[buf][0] + row * 64 +
                                 ((g ^ ((row >> 1) & 3)) << 4));
    }
#pragma unroll
    for (int mf = 0; mf < 4; ++mf)
#pragma unroll
      for (int nf = 0; nf < 4; ++nf)
        acc[mf][nf] = __builtin_amdgcn_mfma_f32_16x16x32_bf16(
            af[mf], bfr[nf], acc[mf][nf], 0, 0, 0);
    SCHEDB();
    BAR();               // all waves done reading buf -> safe to overwrite
    if (it + 1 < 32) GSTAGE(buf);  // tail overrun reads land in-bounds, unread
  }

#pragma unroll
  for (int mf = 0; mf < 4; ++mf)
#pragma unroll
    for (int nf = 0; nf < 4; ++nf)
#pragma unroll
      for (int r = 0; r < 4; ++r) {
        long long m = m0 + wm + mf * 16 + g * 4 + r;
        long long n = n0 + wn + nf * 16 + l16;
        C[m * ldc + n] = f2bf(acc[mf][nf][r] * cscale);
      }
}

// ---------------- NT GEMM (f32 out): 64x128 tiles, BK=32 dbuf, counted vmcnt --
// 512 blocks (2/CU). 4 waves: wave computes 32x64; 3 staging loads/wave/iter.
__global__ __launch_bounds__(256) void gemm_out(
    const unsigned short* __restrict__ A,
    const unsigned short* __restrict__ B,
    float* __restrict__ C) {
  __shared__ unsigned short As[2][2048];   // 64 rows x 32 (64B rows, swizzled)
  __shared__ unsigned short Bs[2][4096];   // 128 rows x 32
  const int tid = threadIdx.x;
  const int wv = tid >> 6, lane = tid & 63;
  const int g = lane >> 4, l16 = lane & 15;
  const int m0 = blockIdx.y * 64, n0 = blockIdx.x * 128;
  const int wm = (wv >> 1) * 32, wn = (wv & 1) * 64;
  const int sro = lane >> 2, sc4 = lane & 3;
  f32x4 acc[2][4] = {};

  const int rA = wv * 16 + sro;
  const int rB0 = wv * 32 + sro, rB1 = wv * 32 + 16 + sro;
  const int cdA = (sc4 ^ ((rA >> 1) & 3)) * 8;
  const int cdB0 = (sc4 ^ ((rB0 >> 1) & 3)) * 8, cdB1 = (sc4 ^ ((rB1 >> 1) & 3)) * 8;
  const unsigned short* Ap = A + (long long)(m0 + rA) * 1024 + cdA;
  const unsigned short* Bp0 = B + (long long)(n0 + rB0) * 1024 + cdB0;
  const unsigned short* Bp1 = B + (long long)(n0 + rB1) * 1024 + cdB1;

#define OSTAGE(BUF)                                                            \
  {                                                                            \
    gload_lds16(Ap, &As[BUF][wv * 512]);                                       \
    gload_lds16(Bp0, &Bs[BUF][wv * 1024]);                                     \
    gload_lds16(Bp1, &Bs[BUF][wv * 1024 + 512]);                               \
    Ap += 32; Bp0 += 32; Bp1 += 32;                                            \
  }

  OSTAGE(0);
  OSTAGE(1);

  for (int it = 0; it < 32; ++it) {
    const int buf = it & 1;
    WAIT_VM3();
    BAR();
    SCHEDB();
    bf16x8 af[2], bfr[4];
#pragma unroll
    for (int mf = 0; mf < 2; ++mf) {
      int row = wm + mf * 16 + l16;
      af[mf] = *(const bf16x8*)((const char*)&As[buf][0] + row * 64 +
                                ((g ^ ((row >> 1) & 3)) << 4));
    }
#pragma unroll
    for (int nf = 0; nf < 4; ++nf) {
      int row = wn + nf * 16 + l16;
      bfr[nf] = *(const bf16x8*)((const char*)&Bs[buf][0] + row * 64 +
                                 ((g ^ ((row >> 1) & 3)) << 4));
    }
#pragma unroll
    for (int mf = 0; mf < 2; ++mf)
#pragma unroll
      for (int nf = 0; nf < 4; ++nf)
        acc[mf][nf] = __builtin_amdgcn_mfma_f32_16x16x32_bf16(
            af[mf], bfr[nf], acc[mf][nf], 0, 0, 0);
    SCHEDB();
    BAR();
    if (it + 1 < 32) OSTAGE(buf);
  }

#pragma unroll
  for (int mf = 0; mf < 2; ++mf)
#pragma unroll
    for (int nf = 0; nf < 4; ++nf)
#pragma unroll
      for (int r = 0; r < 4; ++r) {
        long long m = m0 + wm + mf * 16 + g * 4 + r;
        long long n = n0 + wn + nf * 16 + l16;
        C[m * 1024 + n] = acc[mf][nf][r];
      }
}

// ---------------- flash attention, split-K(8), fixed-ref softmax, ptr staging --
// Round 15 structure; staging via pre-computed per-lane pointers (advance by
// +64 K-rows / +64 V-cols per tile); LDS read offsets hoisted (cb4 shared by
// K and V reads).
__global__ __launch_bounds__(256, 4) void attn_kernel(
    const unsigned short* __restrict__ Qg,
    const unsigned short* __restrict__ Kg,
    const unsigned short* __restrict__ VTg,
    unsigned short* __restrict__ Og,
    unsigned short* __restrict__ pacc,
    float* __restrict__ pml) {
  __shared__ unsigned short Kls[2][4096];  // [buf][key 64][d 64] (chunk-swizzled)
  __shared__ unsigned short Vls[2][4096];  // [buf][d 64][key 64] (chunk-swizzled)

  const int tid = threadIdx.x;
  const int wv = tid >> 6, lane = tid & 63;
  const int l32 = lane & 31, hi = lane >> 5;
  const int h = blockIdx.y, b = blockIdx.z;

  // chunk decode, longest-qt first (LPT)
  const int i = blockIdx.x;  // [0,40)
  int qt, c, cn;
  if (i < 16)      { qt = 15 - (i >> 2); c = i & 3; cn = 4; }
  else if (i < 28) { int j = i - 16; qt = 11 - j / 3; c = j % 3; cn = 3; }
  else if (i < 36) { int j = i - 28; qt = 7 - ((j >> 1)); c = j & 1; cn = 2; }
  else             { qt = 39 - i; c = 0; cn = 1; }

  const int nt = 2 * qt + 2;
  const int t0 = c * 8;
  const int tb = min(t0 + 8, nt);   // block stage bound
  const int umax = 4 * qt + wv;     // last 32-key sub-tile this wave computes

  const int q = qt * 128 + wv * 32 + l32;
  const long long bh = (long long)b * SEQ * DIM + h * HDIM;
  const long long vbase = (long long)h * HDIM * 4096 + b * SEQ;

  // Q fragments (B-operand): B[col=q][k = hi*8+j], per 16-d slice
  const unsigned short* Qrow = Qg + (long long)(b * SEQ + q) * DIM + h * HDIM;
  bf16x8 qf[4];
#pragma unroll
  for (int ds = 0; ds < 4; ++ds)
    qf[ds] = *(const bf16x8*)(Qrow + ds * 16 + hi * 8);
  WAIT_VM0();  // drain Q loads so the staging vmcnt counts are exact

  // all-ones bf16 A-fragment for the l-accumulating MFMA
  bf16x8 ones;
#pragma unroll
  for (int j = 0; j < 8; ++j) ones[j] = (short)0x3F80;

  f32x16 acc0 = {}, acc1 = {}, lacc = {};

  // hoisted LDS read offsets: cb4[k] serves K (ds=k) and V (slice=k)
  const int xm = l32 & 7;
  int cb4_0 = ((0 | hi) ^ xm) * 16;
  int cb4_1 = ((2 | hi) ^ xm) * 16;
  int cb4_2 = ((4 | hi) ^ xm) * 16;
  int cb4_3 = ((6 | hi) ^ xm) * 16;
  const int krb = l32 * 128;

  // staging pointers: wave wv loads K rows {2wv*8.., (2wv+1)*8..} and V rows same
  const int sr = lane >> 3, sc = lane & 7;
  const int r0 = wv * 16 + sr, r1 = wv * 16 + 8 + sr;
  const int cs0 = (sc ^ (r0 & 7)) * 8, cs1 = (sc ^ (r1 & 7)) * 8;
  const unsigned short* Kp0 = Kg + bh + (long long)(t0 * 64 + r0) * DIM + cs0;
  const unsigned short* Kp1 = Kg + bh + (long long)(t0 * 64 + r1) * DIM + cs1;
  const unsigned short* Vp0 = VTg + vbase + (long long)r0 * 4096 + t0 * 64 + cs0;
  const unsigned short* Vp1 = VTg + vbase + (long long)r1 * 4096 + t0 * 64 + cs1;
  const int ld0 = (wv * 16) * 64 + sr * 0;  // dest chunk bases (jj*512)
  // dest offsets: jj0 = 2wv -> 2wv*512 ; jj1 -> (2wv+1)*512

#define STAGE(BUF)                                                             \
  {                                                                            \
    gload_lds16(Kp0, &Kls[BUF][wv * 1024]);                                    \
    gload_lds16(Kp1, &Kls[BUF][wv * 1024 + 512]);                              \
    gload_lds16(Vp0, &Vls[BUF][wv * 1024]);                                    \
    gload_lds16(Vp1, &Vls[BUF][wv * 1024 + 512]);                              \
    Kp0 += 64 * 1024; Kp1 += 64 * 1024; Vp0 += 64; Vp1 += 64;                  \
  }

  STAGE(0);
  STAGE(1);

  for (int t = t0; t < tb; ++t) {
    const int buf = (t - t0) & 1;
    WAIT_VM4();          // tile-t loads landed (t+1's stay in flight)
    BAR();               // all waves' tile-t staging complete
    SCHEDB();

#pragma unroll
    for (int s = 0; s < 2; ++s) {
      const int u = 2 * t + s;
      if (u <= umax) {
        const char* Kb = (const char*)&Kls[buf][0] + s * 4096 + krb;
        // --- QK^T for 32 keys (windowed K reads, hoisted offsets) ---
        f32x16 sv = {};
        __builtin_amdgcn_s_setprio(1);
        sv = mfma32(*(const bf16x8*)(Kb + cb4_0), qf[0], sv);
        sv = mfma32(*(const bf16x8*)(Kb + cb4_1), qf[1], sv);
        sv = mfma32(*(const bf16x8*)(Kb + cb4_2), qf[2], sv);
        sv = mfma32(*(const bf16x8*)(Kb + cb4_3), qf[3], sv);
        __builtin_amdgcn_s_setprio(0);

        // --- causal mask (only the diagonal sub-tile; key base == q base) ---
        if (u == umax) {
#pragma unroll
          for (int r = 0; r < 16; ++r) {
            int kw = (r & 3) + 8 * (r >> 2) + 4 * hi;  // key within 32-block
            if (kw > l32) sv[r] = -1e30f;
          }
        }

        // --- p = exp2(s): single v_exp_f32 (fixed ref; normalization cancels)
#pragma unroll
        for (int r = 0; r < 16; ++r) sv[r] = __builtin_amdgcn_exp2f(sv[r]);

        // --- P -> bf16 B-fragments (in-register) + PV + l via ones-MFMA ---
        const char* Vb0 = (const char*)&Vls[buf][0] + krb;
        const char* Vb1 = Vb0 + 32 * 128;
        __builtin_amdgcn_s_setprio(1);
#pragma unroll
        for (int kk = 0; kk < 2; ++kk) {
          const int base = kk * 8;
          unsigned a0 = cvtpk(sv[base + 0], sv[base + 1]);
          unsigned a1 = cvtpk(sv[base + 2], sv[base + 3]);
          unsigned a2 = cvtpk(sv[base + 4], sv[base + 5]);
          unsigned a3 = cvtpk(sv[base + 6], sv[base + 7]);
          asm("v_permlane32_swap_b32 %0, %1" : "+v"(a0), "+v"(a2));
          asm("v_permlane32_swap_b32 %0, %1" : "+v"(a1), "+v"(a3));
          union { unsigned u4[4]; bf16x8 v; } pf;
          pf.u4[0] = a0; pf.u4[1] = a1; pf.u4[2] = a2; pf.u4[3] = a3;
          const int cbv = (2 * s + kk) == 0 ? cb4_0 : (2 * s + kk) == 1 ? cb4_1
                        : (2 * s + kk) == 2 ? cb4_2 : cb4_3;
          acc0 = mfma32(*(const bf16x8*)(Vb0 + cbv), pf.v, acc0);
          acc1 = mfma32(*(const bf16x8*)(Vb1 + cbv), pf.v, acc1);
          lacc = mfma32(ones, pf.v, lacc);
        }
        __builtin_amdgcn_s_setprio(0);
      }
    }
    SCHEDB();
    BAR();               // all waves done reading buf -> safe to overwrite
    if (t + 1 < tb) STAGE(buf);  // tail overrun reads land in-bounds, unread
  }

  const float l_run = lacc[0];  // every row of lacc holds the column sum l(q)

  if (cn == 1) {
    // --- direct epilogue: O[b, q, h*64 + d] = acc^T / l (cvt_pk packing) ---
    const float inv_l = 1.0f / l_run;
    unsigned short* Orow = Og + (long long)(b * SEQ + q) * DIM + h * HDIM;
#pragma unroll
    for (int dblk = 0; dblk < 2; ++dblk) {
#pragma unroll
      for (int g4 = 0; g4 < 4; ++g4) {
        float v0 = (dblk ? acc1[g4 * 4 + 0] : acc0[g4 * 4 + 0]) * inv_l;
        float v1 = (dblk ? acc1[g4 * 4 + 1] : acc0[g4 * 4 + 1]) * inv_l;
        float v2 = (dblk ? acc1[g4 * 4 + 2] : acc0[g4 * 4 + 2]) * inv_l;
        float v3 = (dblk ? acc1[g4 * 4 + 3] : acc0[g4 * 4 + 3]) * inv_l;
        union { unsigned u[2]; u16x4 v; } o;
        o.u[0] = cvtpk(v0, v1);
        o.u[1] = cvtpk(v2, v3);
        *(u16x4*)(Orow + dblk * 32 + 8 * g4 + 4 * hi) = o.v;
      }
    }
  } else {
    // --- partial epilogue: unnormalized acc (bf16, cvt_pk) + l (f32) ---
    const int sbase = qt < 8 ? 2 * (qt - 4) : qt < 12 ? 8 + 3 * (qt - 8) : 20 + 4 * (qt - 12);
    const int slot = (b * NHEAD + h) * 36 + sbase + c;
    unsigned short* pbase = pacc + (size_t)slot * 8192 + (wv * 32 + l32) * 64;
#pragma unroll
    for (int dblk = 0; dblk < 2; ++dblk) {
#pragma unroll
      for (int g4 = 0; g4 < 4; ++g4) {
        float v0 = dblk ? acc1[g4 * 4 + 0] : acc0[g4 * 4 + 0];
        float v1 = dblk ? acc1[g4 * 4 + 1] : acc0[g4 * 4 + 1];
        float v2 = dblk ? acc1[g4 * 4 + 2] : acc0[g4 * 4 + 2];
        float v3 = dblk ? acc1[g4 * 4 + 3] : acc0[g4 * 4 + 3];
        union { unsigned u[2]; u16x4 v; } o;
        o.u[0] = cvtpk(v0, v1);
        o.u[1] = cvtpk(v2, v3);
        *(u16x4*)(pbase + dblk * 32 + 8 * g4 + 4 * hi) = o.v;
      }
    }
    if (hi == 0) pml[slot * 128 + wv * 32 + l32] = l_run;
  }
}

// ---------------- split-K merge: plain sum (fixed reference => weights 1) ----
__global__ __launch_bounds__(256) void attn_merge(
    const unsigned short* __restrict__ pacc,
    const float* __restrict__ pml,
    unsigned short* __restrict__ Og) {
  const int qt = 4 + blockIdx.x;  // 4..15
  const int h = blockIdx.y, b = blockIdx.z;
  const int cn = (qt >> 2) + 1;
  const int sbase = qt < 8 ? 2 * (qt - 4) : qt < 12 ? 8 + 3 * (qt - 8) : 20 + 4 * (qt - 12);
  const int base_slot = (b * NHEAD + h) * 36 + sbase;
  const int t = threadIdx.x;
  const int ql = t >> 1, d0 = (t & 1) * 32;

  float L = 0.f;
#pragma unroll
  for (int cc = 0; cc < 4; ++cc)
    if (cc < cn) L += pml[(base_slot + cc) * 128 + ql];
  const float invL = 1.0f / L;

  float o[32] = {};
#pragma unroll
  for (int cc = 0; cc < 4; ++cc)
    if (cc < cn) {
      const unsigned short* p = pacc + (size_t)(base_slot + cc) * 8192 + ql * 64 + d0;
#pragma unroll
      for (int k = 0; k < 32; k += 8) {
        u16x8 v = *(const u16x8*)(p + k);
#pragma unroll
        for (int jv = 0; jv < 8; ++jv) o[k + jv] += bf2f(v[jv]);
      }
    }

  const int q = qt * 128 + ql;
  unsigned short* orow = Og + (size_t)(b * SEQ + q) * DIM + h * HDIM + d0;
#pragma unroll
  for (int k = 0; k < 32; k += 8) {
    union { unsigned u[4]; u16x8 v; } ov;
#pragma unroll
    for (int jv = 0; jv < 4; ++jv)
      ov.u[jv] = cvtpk(o[k + 2 * jv] * invL, o[k + 2 * jv + 1] * invL);
    *(u16x8*)(orow + k) = ov.v;
  }
}

// ---------------- launcher ----------------
extern "C" void kernel_launch(void* const* d_in, const int* in_sizes, int n_in,
                              void* d_out, int out_size, void* d_ws, size_t ws_size,
                              hipStream_t stream) {
  const float* x   = (const float*)d_in[0];
  const float* wq  = (const float*)d_in[2];
  const float* wk  = (const float*)d_in[3];
  const float* wv_ = (const float*)d_in[4];
  const float* wo  = (const float*)d_in[5];

  unsigned short* xb  = (unsigned short*)d_ws;            // [4096][1024]
  unsigned short* wb  = xb + (size_t)4096 * 1024;         // [4][1024][1024] q,k,v,o
  unsigned short* qkv = wb + (size_t)4 * 1024 * 1024;     // Q,K [4096][1024]; VT [1024][4096]
  unsigned short* ao  = qkv + (size_t)3 * 4096 * 1024;    // [4096][1024]
  unsigned short* pacc = ao + (size_t)4096 * 1024;        // [1152][128][64] bf16 partial acc
  float* pml = (float*)(pacc + (size_t)1152 * 8192);      // [1152][128] f32 l

  f2bf_all<<<8192, 256, 0, stream>>>(x, wq, wk, wv_, wo, xb, wb);

  // Q, K, V^T projections in ONE launch (768 blocks); Q pre-scaled by C2
  gemm3<<<768, 256, 0, stream>>>(xb, wb, qkv);

  attn_kernel<<<dim3(40, 16, 2), 256, 0, stream>>>(
      qkv, qkv + 4194304, qkv + 2 * 4194304, ao, pacc, pml);

  attn_merge<<<dim3(12, 16, 2), 256, 0, stream>>>(pacc, pml, ao);

  // output projection -> fp32 d_out
  gemm_out<<<dim3(8, 64), 256, 0, stream>>>(ao, wb + 3145728, (float*)d_out);
}